// Round 7
// baseline (382.759 us; speedup 1.0000x reference)
//
#include <hip/hip_runtime.h>

// SSIM on (32,3,512,512) f32 — wave-autonomous separable 11-tap streaming.
// R15: R6 structure (1 col/lane, 4-chain (x-y)^2 basis, 3 blk/CU) with the
// per-step overhead cut that R6's counters demanded:
//  - R6 confirmed 3 waves/SIMD resident (VALUBusy 60% = 3 x 77k/386k) but
//    total VALU issue ROSE vs R0 (237M vs 189M SIMD-cyc): per-step fixed
//    overhead (clamps, VM masks, 64b address math, fq muls ~130 instr) is
//    amortized over 1 col instead of 2.
//  - Fix 1: peel. Rows can only be OOB in steps 0..11 / 129..137. The 117
//    steady steps use UNIFORM row pointers (SGPR, +=512/step via s_add,
//    co-issues with VALU) and raw unmasked stores. Clamp/mask code only in
//    the peeled 21 steps (compile-time i -> emit checks fold away).
//  - Fix 2: symmetric folding. g[j]==g[10-j] exactly (row sums of a
//    symmetric outer product), so h-conv folds to 5 pairs + center:
//    88 -> 66 VALU/step, accumulator chains halve.
//  - Emit math, PF ring, LDS layout, reduction: byte-identical to R6.
// Occupancy model (R0-R6): HW packs floor(512/(2 x VGPR)) waves/SIMD;
// attr(3,4) keeps codegen budget 85 >= ~75 live -> no spill.
// Sentinel: WRITE_SIZE ~48KB. Predict kernel 95-115us.

#define NBLK 768

// ---- vertical shift-register chains: 10 regs x 4 quantities (scalar) ----
#define DECL_CH(C) float C##0=0.f,C##1=0.f,C##2=0.f,C##3=0.f,C##4=0.f, \
                         C##5=0.f,C##6=0.f,C##7=0.f,C##8=0.f,C##9=0.f;
#define SHIFT(C, H) \
  C##9 = fmaf(g9, H, C##8); C##8 = fmaf(g8, H, C##7); C##7 = fmaf(g7, H, C##6); \
  C##6 = fmaf(g6, H, C##5); C##5 = fmaf(g5, H, C##4); C##4 = fmaf(g4, H, C##3); \
  C##3 = fmaf(g3, H, C##2); C##2 = fmaf(g2, H, C##1); C##1 = fmaf(g1, H, C##0); \
  C##0 = g0 * H;

// ---- folded horizontal conv: pair (J,10-J) shares gJ (exactly symmetric) ----
#define HPAIR(GJ, QA, QB) { \
  const float xa=(QA).x, ya=(QA).y, xb=(QB).x, yb=(QB).y; \
  HX = fmaf(GJ, xa+xb, HX); \
  HY = fmaf(GJ, ya+yb, HY); \
  const float da = xa-ya, db = xb-yb; \
  float qd = da*da; qd = fmaf(db, db, qd); \
  HD = fmaf(GJ, qd, HD); \
  float qp = xa*ya; qp = fmaf(xb, yb, qp); \
  HP = fmaf(GJ, qp, HP); }

// reads q0..q10 from lsw, produces HX,HY,HD,HP
#define HCONV_BODY \
  const float2 q0 = lsw[lane  ], q1 = lsw[lane+1], q2 = lsw[lane+2]; \
  const float2 q3 = lsw[lane+3], q4 = lsw[lane+4], q5 = lsw[lane+5]; \
  const float2 q6 = lsw[lane+6], q7 = lsw[lane+7], q8 = lsw[lane+8]; \
  const float2 q9 = lsw[lane+9], q10 = lsw[lane+10]; \
  const float xc = q5.x, yc = q5.y, dc = xc - yc; \
  float HX = g5*xc, HY = g5*yc, HD = (g5*dc)*dc, HP = (g5*xc)*yc; \
  HPAIR(g0, q0, q10) HPAIR(g1, q1, q9) HPAIR(g2, q2, q8) \
  HPAIR(g3, q3, q7)  HPAIR(g4, q4, q6)

// emit output row (identical arithmetic to R6)
#define EMIT(TS) { \
    const float mux = fmaf(g10, HX, CX9); \
    const float muy = fmaf(g10, HY, CY9); \
    const float ed  = fmaf(g10, HD, CD9); \
    const float ep  = fmaf(g10, HP, CP9); \
    const float mud  = mux - muy; \
    const float vard = fmaf(-mud, mud, ed); \
    const float vp   = fmaf(-mux, muy, ep); \
    const float vs   = fmaf(2.f, vp, vard); \
    const float mux2 = mux*mux, muy2 = muy*muy, muxy = mux*muy; \
    const float num = fmaf(2.f, muxy, C1) * fmaf(2.f, vp, C2); \
    const float den = (mux2 + muy2 + C1) * (vs + C2); \
    TS += num * __builtin_amdgcn_rcpf(den); }

// ---- peeled step: clamped addressing + validity masks (compile-time I) ----
#define STEP_CLAMP(I, P, Q, TS) { \
  const int i_ = (I); \
  const int rl = r0 - 2 + i_; \
  VM##P = ((unsigned)rl < 512u) ? 1.f : 0.f; \
  { const int rlc = (rl < 0) ? 0 : ((rl > 511) ? 511 : rl); \
    const float* xp = xplane + (rlc << 9); \
    const float* yp = yplane + (rlc << 9); \
    PF##P##mx = xp[mcol]; PF##P##my = yp[mcol]; \
    PF##P##hx = xp[hcolC]; PF##P##hy = yp[hcolC]; } \
  HCONV_BODY \
  if (i_ >= 10) EMIT(TS) \
  SHIFT(CX, HX) SHIFT(CY, HY) SHIFT(CD, HD) SHIFT(CP, HP) \
  { const float fq = VM##Q; const float fh = fq * hmask; \
    lsw[lane + 5] = make_float2(fq * PF##Q##mx, fq * PF##Q##my); \
    if (lane < 10) lsw[hslot] = make_float2(fh * PF##Q##hx, fh * PF##Q##hy); } }

// ---- steady step: uniform row pointers, no clamps/masks, always emits ----
#define STEP_FAST(P, Q, TS) { \
  PF##P##mx = xrow[mcol]; PF##P##my = yrow[mcol]; \
  PF##P##hx = xrow[hcolC]; PF##P##hy = yrow[hcolC]; \
  xrow += 512; yrow += 512; \
  HCONV_BODY \
  EMIT(TS) \
  SHIFT(CX, HX) SHIFT(CY, HY) SHIFT(CD, HD) SHIFT(CP, HP) \
  lsw[lane + 5] = make_float2(PF##Q##mx, PF##Q##my); \
  if (lane < 10) lsw[hslot] = make_float2(hmask * PF##Q##hx, hmask * PF##Q##hy); }

__global__ __launch_bounds__(256)
__attribute__((amdgpu_waves_per_eu(3, 4)))
void ssim_fused(
    const float* __restrict__ x, const float* __restrict__ y,
    const float* __restrict__ window,
    unsigned* __restrict__ counter, float* __restrict__ partials,
    float* __restrict__ out)
{
    const int tid  = threadIdx.x;
    const int lane = tid & 63;
    // wave id is uniform: force SGPR lineage so plane/row pointers stay scalar
    const int wv   = __builtin_amdgcn_readfirstlane(tid >> 6);
    const int W    = blockIdx.x * 4 + wv;   // 0..3071
    const int img  = W >> 5;                // 96 planes, 32 waves each
    const int w5   = W & 31;
    const int cb   = w5 >> 2;               // 8 col bands x 64
    const int rb   = w5 & 3;                // 4 row bands x 128
    const int r0   = rb << 7;
    const int c0   = cb << 6;

    const float* xplane = x + (size_t)img * 262144;
    const float* yplane = y + (size_t)img * 262144;

    // halo geometry (time-invariant): slots 0..4 left, 69..73 right
    const int  hslot = (lane < 5) ? lane : (64 + lane);          // lanes 5..9 -> 69..73
    const int  hcol  = (lane < 5) ? (c0 - 5 + lane) : (c0 + 59 + lane);
    const float hmask = (lane < 10 && hcol >= 0 && hcol < 512) ? 1.f : 0.f;
    const int  hcolC = (hcol < 0) ? 0 : ((hcol > 511) ? 511 : hcol);
    const int  mcol  = c0 + lane;

    // 1-D gaussian (row sums of outer(g,g)); uniform -> SGPR via readfirstlane
    float gtmp[11];
    #pragma unroll
    for (int ii = 0; ii < 11; ++ii) {
        float s = 0.f;
        #pragma unroll
        for (int jj = 0; jj < 11; ++jj) s += window[ii * 11 + jj];
        gtmp[ii] = s;
    }
    #define SG(N) const float g##N = __uint_as_float(__builtin_amdgcn_readfirstlane(__float_as_uint(gtmp[N])));
    SG(0) SG(1) SG(2) SG(3) SG(4) SG(5) SG(6) SG(7) SG(8) SG(9) SG(10)

    // wave-private LDS row: slot s = float2(x,y) for col c0-5+s, s in [0,74)
    __shared__ float2 ls2[4][74];
    float2* lsw = ls2[wv];

    DECL_CH(CX) DECL_CH(CY) DECL_CH(CD) DECL_CH(CP)

    // prefetch ring state (scalar: main x,y + halo x,y)
    float PF0mx, PF0my, PF0hx, PF0hy; float VM0 = 0.f;
    float PF1mx, PF1my, PF1hx, PF1hy; float VM1;
    float PF2mx, PF2my, PF2hx, PF2hy; float VM2;

    // prime LDS with row r0-5 (read at step 0)
    {
        const int rl = r0 - 5;
        const float fq = (rl >= 0) ? 1.f : 0.f;
        const int rlc = (rl < 0) ? 0 : rl;
        const float* xp = xplane + (rlc << 9);
        const float* yp = yplane + (rlc << 9);
        const float fh = fq * hmask;
        lsw[lane + 5] = make_float2(fq * xp[mcol], fq * yp[mcol]);
        if (lane < 10) lsw[hslot] = make_float2(fh * xp[hcolC], fh * yp[hcolC]);
    }
    // prime PF1 <- row r0-4 (stored end of step 0), PF2 <- row r0-3 (step 1)
    {
        const int rl = r0 - 4;
        VM1 = (rl >= 0) ? 1.f : 0.f;
        const int rlc = (rl < 0) ? 0 : rl;
        const float* xp = xplane + (rlc << 9);
        const float* yp = yplane + (rlc << 9);
        PF1mx = xp[mcol]; PF1my = yp[mcol];
        PF1hx = xp[hcolC]; PF1hy = yp[hcolC];
    }
    {
        const int rl = r0 - 3;
        VM2 = (rl >= 0) ? 1.f : 0.f;
        const int rlc = (rl < 0) ? 0 : rl;
        const float* xp = xplane + (rlc << 9);
        const float* yp = yplane + (rlc << 9);
        PF2mx = xp[mcol]; PF2my = yp[mcol];
        PF2hx = xp[hcolC]; PF2hy = yp[hcolC];
    }

    float tsA = 0.f, tsB = 0.f, tsC = 0.f;
    const float C1 = 1e-4f, C2 = 9e-4f;

    // prologue: steps 0..11 (clamped; covers all low-edge loads/stores/emits)
    STEP_CLAMP(0, 0, 1, tsA) STEP_CLAMP(1, 1, 2, tsB) STEP_CLAMP(2, 2, 0, tsC)
    STEP_CLAMP(3, 0, 1, tsA) STEP_CLAMP(4, 1, 2, tsB) STEP_CLAMP(5, 2, 0, tsC)
    STEP_CLAMP(6, 0, 1, tsA) STEP_CLAMP(7, 1, 2, tsB) STEP_CLAMP(8, 2, 0, tsC)
    STEP_CLAMP(9, 0, 1, tsA) STEP_CLAMP(10, 1, 2, tsB) STEP_CLAMP(11, 2, 0, tsC)

    // steady: steps 12..128 (rows r0+10..r0+126, always in [4,510] -> no
    // clamps; uniform SGPR row pointers, s_add per step)
    const float* xrow = xplane + ((r0 + 10) << 9);
    const float* yrow = yplane + ((r0 + 10) << 9);
    #pragma unroll 1
    for (int it = 0; it < 39; ++it) {
        STEP_FAST(0, 1, tsA) STEP_FAST(1, 2, tsB) STEP_FAST(2, 0, tsC)
    }

    // tail: steps 129..137 (clamped+masked; VM0/1/2 are all 1.f on entry,
    // correct for the steady-loaded rows they store)
    STEP_CLAMP(129, 0, 1, tsA) STEP_CLAMP(130, 1, 2, tsB) STEP_CLAMP(131, 2, 0, tsC)
    STEP_CLAMP(132, 0, 1, tsA) STEP_CLAMP(133, 1, 2, tsB) STEP_CLAMP(134, 2, 0, tsC)
    STEP_CLAMP(135, 0, 1, tsA) STEP_CLAMP(136, 1, 2, tsB) STEP_CLAMP(137, 2, 0, tsC)

    // ---- block partial -> global; last block reduces all ----
    float t = (tsA + tsB) + tsC;
    #pragma unroll
    for (int off = 32; off > 0; off >>= 1) t += __shfl_down(t, off, 64);
    __shared__ float wsum[4];
    __shared__ int   sflag;
    if (lane == 0) wsum[wv] = t;
    __syncthreads();
    if (tid == 0) {
        partials[blockIdx.x] = (wsum[0] + wsum[1]) + (wsum[2] + wsum[3]);
        __threadfence();
        const unsigned old = atomicAdd(counter, 1u);
        sflag = (old == NBLK - 1) ? 1 : 0;
    }
    __syncthreads();
    if (sflag) {
        __threadfence();
        double s = 0.0;
        for (int idx = tid; idx < NBLK; idx += 256) s += (double)partials[idx];
        #pragma unroll
        for (int off = 32; off > 0; off >>= 1) s += __shfl_down(s, off, 64);
        __shared__ double dsum[4];
        if (lane == 0) dsum[wv] = s;
        __syncthreads();
        if (tid == 0)
            out[0] = (float)(((dsum[0] + dsum[1]) + (dsum[2] + dsum[3])) / 25165824.0);
    }
}

extern "C" void kernel_launch(void* const* d_in, const int* in_sizes, int n_in,
                              void* d_out, int out_size, void* d_ws, size_t ws_size,
                              hipStream_t stream)
{
    const float* x = (const float*)d_in[0];
    const float* y = (const float*)d_in[1];
    const float* w = (const float*)d_in[2];
    unsigned* counter = (unsigned*)d_ws;                     // zeroed below
    float* partials   = (float*)((char*)d_ws + 256);         // 768 floats

    hipMemsetAsync(d_ws, 0, 4, stream);                      // capture-safe
    ssim_fused<<<NBLK, 256, 0, stream>>>(x, y, w, counter, partials, (float*)d_out);
}

// Round 12
// 286.480 us; speedup vs baseline: 1.3361x; 1.3361x over previous
//
#include <hip/hip_runtime.h>

// SSIM on (32,3,512,512) f32 — wave-autonomous separable 11-tap streaming.
// R19: R6's EXACT green FP arithmetic (unfolded HTAP, 4-chain (x-y)^2
// basis, runtime emit guard — bit-stable at absmax 2.441406e-4 across
// R0/R3/R6) with ONE schedule change: depth-6 prefetch ring, store-at-top.
//
// Why: R6 counters show per-step wall 2800 cyc vs ~550 issued — 80% wave
// stall. Suspect: end-of-step LDS store consumes loads only 2 steps old
// (vmcnt slack ~8, or 0 if alias analysis degrades) -> every step pays
// load latency. Fix: 6-slot ring; step i FIRST stores slot i%6 (loaded 6
// steps ago -> 20 younger loads of waitcnt slack), THEN reloads that slot
// (row r0+1+i), then h-conv/emit/shift. Load->consume distance 3->6 steps.
// Zero FP-sequence change (fold abandoned: R16/R17/R18 failed, and
// R17-vs-R18 bit-identical-source divergence proved ffp-contract build
// lottery — only the long-proven unfolded sequence is trusted).
// Ring regs +15 -> ~83 live; attr(3,4) budget 85. Sentinel: WRITE ~48KB.
// numerics sentinel: absmax must be exactly 2.441406e-4.

#define NBLK 768

// ---- vertical shift-register chains: 10 regs x 4 quantities (scalar) ----
#define DECL_CH(C) float C##0=0.f,C##1=0.f,C##2=0.f,C##3=0.f,C##4=0.f, \
                         C##5=0.f,C##6=0.f,C##7=0.f,C##8=0.f,C##9=0.f;
#define SHIFT(C, H) \
  C##9 = fmaf(g9, H, C##8); C##8 = fmaf(g8, H, C##7); C##7 = fmaf(g7, H, C##6); \
  C##6 = fmaf(g6, H, C##5); C##5 = fmaf(g5, H, C##4); C##4 = fmaf(g4, H, C##3); \
  C##3 = fmaf(g3, H, C##2); C##2 = fmaf(g2, H, C##1); C##1 = fmaf(g1, H, C##0); \
  C##0 = g0 * H;

// ---- UNFOLDED horizontal tap (R6-exact, do not touch) ----
#define HTAP(J, QV) { const float gj = g##J; \
  const float xv = (QV).x, yv = (QV).y; \
  const float t1 = gj * xv, t2 = gj * yv; \
  const float dv = xv - yv, td = gj * dv; \
  HX += t1; HY += t2; \
  HD = fmaf(td, dv, HD); \
  HP = fmaf(t1, yv, HP); }

// prime ring slot S with row r0-5+S (low clamp only; r0-5+S <= 384)
#define PRIME(S) { \
    const int rl = r0 - 5 + (S); \
    VM##S = (rl >= 0) ? 1.f : 0.f; \
    const int rlc = (rl < 0) ? 0 : rl; \
    const float* xp = xplane + (rlc << 9); \
    const float* yp = yplane + (rlc << 9); \
    PF##S##mx = xp[mcol]; PF##S##my = yp[mcol]; \
    PF##S##hx = xp[hcolC]; PF##S##hy = yp[hcolC]; }

// One step (runtime I, literal slot S):
//  1) store slot S (row r0-5+I, loaded 6 steps ago / primed) to LDS
//  2) reload slot S with row r0+1+I (high clamp only; r0+1+I >= 1)
//  3) h-conv of the just-stored row, emit if I>=10, shift chains
#define STEP6(I, S, TS) { \
  const int i_ = (I); \
  { const float fq = VM##S; const float fh = fq * hmask; \
    lsw[lane + 5] = make_float2(fq * PF##S##mx, fq * PF##S##my); \
    if (lane < 10) lsw[hslot] = make_float2(fh * PF##S##hx, fh * PF##S##hy); } \
  { const int rl = r0 + 1 + i_; \
    VM##S = ((unsigned)rl < 512u) ? 1.f : 0.f; \
    const int rlc = (rl > 511) ? 511 : rl; \
    const float* xp = xplane + (rlc << 9); \
    const float* yp = yplane + (rlc << 9); \
    PF##S##mx = xp[mcol]; PF##S##my = yp[mcol]; \
    PF##S##hx = xp[hcolC]; PF##S##hy = yp[hcolC]; } \
  const float2 q0 = lsw[lane  ], q1 = lsw[lane+1], q2 = lsw[lane+2]; \
  const float2 q3 = lsw[lane+3], q4 = lsw[lane+4], q5 = lsw[lane+5]; \
  const float2 q6 = lsw[lane+6], q7 = lsw[lane+7], q8 = lsw[lane+8]; \
  const float2 q9 = lsw[lane+9], q10 = lsw[lane+10]; \
  float HX = 0.f, HY = 0.f, HD = 0.f, HP = 0.f; \
  HTAP(0,q0) HTAP(1,q1) HTAP(2,q2) HTAP(3,q3) HTAP(4,q4) HTAP(5,q5) \
  HTAP(6,q6) HTAP(7,q7) HTAP(8,q8) HTAP(9,q9) HTAP(10,q10) \
  if (i_ >= 10) { \
    const float mux = fmaf(g10, HX, CX9); \
    const float muy = fmaf(g10, HY, CY9); \
    const float ed  = fmaf(g10, HD, CD9); \
    const float ep  = fmaf(g10, HP, CP9); \
    const float mud  = mux - muy; \
    const float vard = fmaf(-mud, mud, ed); \
    const float vp   = fmaf(-mux, muy, ep); \
    const float vs   = fmaf(2.f, vp, vard); \
    const float mux2 = mux*mux, muy2 = muy*muy, muxy = mux*muy; \
    const float num = fmaf(2.f, muxy, C1) * fmaf(2.f, vp, C2); \
    const float den = (mux2 + muy2 + C1) * (vs + C2); \
    TS += num * __builtin_amdgcn_rcpf(den); \
  } \
  SHIFT(CX, HX) SHIFT(CY, HY) SHIFT(CD, HD) SHIFT(CP, HP) }

__global__ __launch_bounds__(256)
__attribute__((amdgpu_waves_per_eu(3, 4)))
void ssim_fused(
    const float* __restrict__ x, const float* __restrict__ y,
    const float* __restrict__ window,
    unsigned* __restrict__ counter, float* __restrict__ partials,
    float* __restrict__ out)
{
    const int tid  = threadIdx.x;
    const int lane = tid & 63;
    // wave id is uniform: force SGPR lineage so plane pointers stay scalar
    const int wv   = __builtin_amdgcn_readfirstlane(tid >> 6);
    const int W    = blockIdx.x * 4 + wv;   // 0..3071
    const int img  = W >> 5;                // 96 planes, 32 waves each
    const int w5   = W & 31;
    const int cb   = w5 >> 2;               // 8 col bands x 64
    const int rb   = w5 & 3;                // 4 row bands x 128
    const int r0   = rb << 7;
    const int c0   = cb << 6;

    const float* xplane = x + (size_t)img * 262144;
    const float* yplane = y + (size_t)img * 262144;

    // halo geometry (time-invariant): slots 0..4 left, 69..73 right
    const int  hslot = (lane < 5) ? lane : (64 + lane);          // lanes 5..9 -> 69..73
    const int  hcol  = (lane < 5) ? (c0 - 5 + lane) : (c0 + 59 + lane);
    const float hmask = (lane < 10 && hcol >= 0 && hcol < 512) ? 1.f : 0.f;
    const int  hcolC = (hcol < 0) ? 0 : ((hcol > 511) ? 511 : hcol);
    const int  mcol  = c0 + lane;

    // 1-D gaussian (row sums of outer(g,g)); uniform -> SGPR via readfirstlane
    float gtmp[11];
    #pragma unroll
    for (int ii = 0; ii < 11; ++ii) {
        float s = 0.f;
        #pragma unroll
        for (int jj = 0; jj < 11; ++jj) s += window[ii * 11 + jj];
        gtmp[ii] = s;
    }
    #define SG(N) const float g##N = __uint_as_float(__builtin_amdgcn_readfirstlane(__float_as_uint(gtmp[N])));
    SG(0) SG(1) SG(2) SG(3) SG(4) SG(5) SG(6) SG(7) SG(8) SG(9) SG(10)

    // wave-private LDS row: slot s = float2(x,y) for col c0-5+s, s in [0,74)
    __shared__ float2 ls2[4][74];
    float2* lsw = ls2[wv];

    DECL_CH(CX) DECL_CH(CY) DECL_CH(CD) DECL_CH(CP)

    // depth-6 prefetch ring (scalar: main x,y + halo x,y + validity)
    float PF0mx, PF0my, PF0hx, PF0hy; float VM0;
    float PF1mx, PF1my, PF1hx, PF1hy; float VM1;
    float PF2mx, PF2my, PF2hx, PF2hy; float VM2;
    float PF3mx, PF3my, PF3hx, PF3hy; float VM3;
    float PF4mx, PF4my, PF4hx, PF4hy; float VM4;
    float PF5mx, PF5my, PF5hx, PF5hy; float VM5;

    // prime slots 0..5 with rows r0-5..r0 (stored at tops of steps 0..5)
    PRIME(0) PRIME(1) PRIME(2) PRIME(3) PRIME(4) PRIME(5)

    float tsA = 0.f, tsB = 0.f, tsC = 0.f;
    const float C1 = 1e-4f, C2 = 9e-4f;

    // 138 steps = 23 x 6 (ring period); emits for i in [10,138).
    // Step i: store row r0-5+i (from slot i%6), reload slot with row
    // r0+1+i, h-conv, emit, shift. ts grouping = i mod 3 (R6-identical).
    #pragma unroll 1
    for (int it = 0; it < 23; ++it) {
        const int i0 = it * 6;
        STEP6(i0 + 0, 0, tsA)
        STEP6(i0 + 1, 1, tsB)
        STEP6(i0 + 2, 2, tsC)
        STEP6(i0 + 3, 3, tsA)
        STEP6(i0 + 4, 4, tsB)
        STEP6(i0 + 5, 5, tsC)
    }

    // ---- block partial -> global; last block reduces all ----
    float t = (tsA + tsB) + tsC;
    #pragma unroll
    for (int off = 32; off > 0; off >>= 1) t += __shfl_down(t, off, 64);
    __shared__ float wsum[4];
    __shared__ int   sflag;
    if (lane == 0) wsum[wv] = t;
    __syncthreads();
    if (tid == 0) {
        partials[blockIdx.x] = (wsum[0] + wsum[1]) + (wsum[2] + wsum[3]);
        __threadfence();
        const unsigned old = atomicAdd(counter, 1u);
        sflag = (old == NBLK - 1) ? 1 : 0;
    }
    __syncthreads();
    if (sflag) {
        __threadfence();
        double s = 0.0;
        for (int idx = tid; idx < NBLK; idx += 256) s += (double)partials[idx];
        #pragma unroll
        for (int off = 32; off > 0; off >>= 1) s += __shfl_down(s, off, 64);
        __shared__ double dsum[4];
        if (lane == 0) dsum[wv] = s;
        __syncthreads();
        if (tid == 0)
            out[0] = (float)(((dsum[0] + dsum[1]) + (dsum[2] + dsum[3])) / 25165824.0);
    }
}

extern "C" void kernel_launch(void* const* d_in, const int* in_sizes, int n_in,
                              void* d_out, int out_size, void* d_ws, size_t ws_size,
                              hipStream_t stream)
{
    const float* x = (const float*)d_in[0];
    const float* y = (const float*)d_in[1];
    const float* w = (const float*)d_in[2];
    unsigned* counter = (unsigned*)d_ws;                     // zeroed below
    float* partials   = (float*)((char*)d_ws + 256);         // 768 floats

    hipMemsetAsync(d_ws, 0, 4, stream);                      // capture-safe
    ssim_fused<<<NBLK, 256, 0, stream>>>(x, y, w, counter, partials, (float*)d_out);
}